// Round 1
// baseline (188.642 us; speedup 1.0000x reference)
//
#include <hip/hip_runtime.h>

typedef __bf16 bf16;
typedef bf16 bf16x8 __attribute__((ext_vector_type(8)));
typedef float f32x4 __attribute__((ext_vector_type(4)));
typedef unsigned short u16;
typedef u16 u16x4 __attribute__((ext_vector_type(4)));

typedef const __attribute__((address_space(1))) void* gptr_t;
typedef __attribute__((address_space(3))) void* sptr_t;

__device__ __forceinline__ void async16(const void* g, void* l) {
  __builtin_amdgcn_global_load_lds((gptr_t)g, (sptr_t)l, 16, 0, 0);
}
__device__ __forceinline__ u16 f2bf(float v) {
  return __builtin_bit_cast(u16, (bf16)v);
}

// ---------------- W transpose (f32 [K][N] -> bf16 [N][K]) ----------------
__global__ void kTransW(const float* __restrict__ Wq, const float* __restrict__ Wk,
                        const float* __restrict__ Wv, const float* __restrict__ Wo,
                        u16* __restrict__ Wt) {
  __shared__ float tile[32][33];
  const int z = blockIdx.z;
  const float* src = (z == 0) ? Wq : (z == 1) ? Wk : (z == 2) ? Wv : Wo;
  const int n0 = blockIdx.x * 32, k0 = blockIdx.y * 32;
  const int tx = threadIdx.x, ty = threadIdx.y;
#pragma unroll
  for (int j = 0; j < 4; ++j)
    tile[ty + j * 8][tx] = src[(size_t)(k0 + ty + j * 8) * 1024 + n0 + tx];
  __syncthreads();
#pragma unroll
  for (int j = 0; j < 4; ++j)
    Wt[(size_t)z * 1048576 + (size_t)(n0 + ty + j * 8) * 1024 + k0 + tx] =
        f2bf(tile[tx][ty + j * 8]);
}

// ---------------- src pack f32 -> bf16 ----------------
__global__ void kPack(const float* __restrict__ x, u16* __restrict__ y) {
  const int i = (blockIdx.x * 256 + threadIdx.x) * 4;
  float4 v = *(const float4*)&x[i];
  u16x4 o = {f2bf(v.x), f2bf(v.y), f2bf(v.z), f2bf(v.w)};
  *(u16x4*)&y[i] = o;
}

// ---------------- GEMM 128x128 tile, BK=32, 4 waves ----------------
// A [4096][1024] bf16 row-major; Bt [N][1024] bf16 (pre-transposed W).
// EPI=0: fused QKV scatter (outQ = Q base; K at +4M elems, Vt at +8M elems)
// EPI=1: plain f32 out [4096][1024] + bias b0
template <int EPI>
__global__ __launch_bounds__(256, 2) void kGemm(
    const u16* __restrict__ A, const u16* __restrict__ Bt,
    const float* __restrict__ b0, const float* __restrict__ b1,
    const float* __restrict__ b2, u16* __restrict__ outQ,
    float* __restrict__ outF) {
  __shared__ __align__(16) u16 As[128 * 32];
  __shared__ __align__(16) u16 Bs[128 * 32];
  const int tid = threadIdx.x, l = tid & 63, w = tid >> 6;
  const int mb = blockIdx.x & 31, nb = blockIdx.x >> 5;
  const int mbase = mb * 128, nbase = nb * 128;
  const int wr = (w >> 1) * 64, wc = (w & 1) * 64;
  f32x4 acc[4][4];
#pragma unroll
  for (int i = 0; i < 4; ++i)
#pragma unroll
    for (int j = 0; j < 4; ++j) acc[i][j] = (f32x4){0.f, 0.f, 0.f, 0.f};

  for (int kt = 0; kt < 32; ++kt) {
    __syncthreads();
#pragma unroll
    for (int i = 0; i < 2; ++i) {
      const int q = (w * 2 + i) * 64 + l;
      const int r = q >> 2, sl = q & 3;
      const int ksw = (sl ^ ((r >> 1) & 3)) * 8;  // source-side XOR swizzle
      async16(&A[(size_t)(mbase + r) * 1024 + kt * 32 + ksw], &As[(w * 2 + i) * 512]);
      async16(&Bt[(size_t)(nbase + r) * 1024 + kt * 32 + ksw], &Bs[(w * 2 + i) * 512]);
    }
    __syncthreads();
    bf16x8 a[4], b[4];
#pragma unroll
    for (int mf = 0; mf < 4; ++mf) {
      const int row = wr + mf * 16 + (l & 15);
      const int slot = (l >> 4) ^ ((row >> 1) & 3);
      a[mf] = *(const bf16x8*)&As[row * 32 + slot * 8];
    }
#pragma unroll
    for (int nf = 0; nf < 4; ++nf) {
      const int row = wc + nf * 16 + (l & 15);
      const int slot = (l >> 4) ^ ((row >> 1) & 3);
      b[nf] = *(const bf16x8*)&Bs[row * 32 + slot * 8];
    }
#pragma unroll
    for (int mf = 0; mf < 4; ++mf)
#pragma unroll
      for (int nf = 0; nf < 4; ++nf)
        acc[mf][nf] = __builtin_amdgcn_mfma_f32_16x16x32_bf16(a[mf], b[nf],
                                                              acc[mf][nf], 0, 0, 0);
  }

  if constexpr (EPI == 0) {
    const int mat = nb >> 3;  // 0:Q 1:K 2:V (blocks never straddle 1024-col bnd)
    const float* bias = (mat == 0) ? b0 : (mat == 1) ? b1 : b2;
    u16* Qo = outQ;
    u16* Ko = outQ + 4 * 1048576;
    u16* Vo = outQ + 8 * 1048576;
#pragma unroll
    for (int nf = 0; nf < 4; ++nf) {
      const int n = nbase + wc + nf * 16 + (l & 15);
      const int c = n & 1023, h = c >> 6, d = c & 63;
      const float bsv = bias[c];
#pragma unroll
      for (int mf = 0; mf < 4; ++mf)
#pragma unroll
        for (int r = 0; r < 4; ++r) {
          const int m = mbase + wr + mf * 16 + (l >> 4) * 4 + r;
          const int bb = m >> 11, t = m & 2047;
          const u16 hv = f2bf(acc[mf][nf][r] + bsv);
          if (mat == 0)
            Qo[((size_t)(bb * 16 + h) * 2048 + t) * 64 + d] = hv;
          else if (mat == 1)
            Ko[((size_t)(bb * 16 + h) * 2048 + t) * 64 + d] = hv;
          else  // V stored transposed: [b][h][d][t]
            Vo[((size_t)(bb * 16 + h) * 64 + d) * 2048 + t] = hv;
        }
    }
  } else {
#pragma unroll
    for (int nf = 0; nf < 4; ++nf) {
      const int n = nbase + wc + nf * 16 + (l & 15);
      const float bsv = b0[n];
#pragma unroll
      for (int mf = 0; mf < 4; ++mf)
#pragma unroll
        for (int r = 0; r < 4; ++r) {
          const int m = mbase + wr + mf * 16 + (l >> 4) * 4 + r;
          outF[(size_t)m * 1024 + n] = acc[mf][nf][r] + bsv;
        }
    }
  }
}

// ---------------- flash attention, causal ----------------
// Q,K: [b][h][2048][64] bf16; Vt: [b][h][64][2048] bf16; AO: [4096][1024] bf16
__global__ __launch_bounds__(256, 2) void kAttn(const u16* __restrict__ Q,
                                                const u16* __restrict__ K,
                                                const u16* __restrict__ Vt,
                                                u16* __restrict__ AO) {
  __shared__ __align__(16) u16 Ksh[64 * 64];
  __shared__ __align__(16) u16 Vsh[64 * 64];
  __shared__ __align__(16) u16 Pl[4][16 * 72];  // per-wave P, row stride 72 (144B)
  const int tid = threadIdx.x, l = tid & 63, w = tid >> 6;
  const int qt = blockIdx.x, bh = blockIdx.y;
  const size_t head = (size_t)bh * 131072;  // 2048*64 == 64*2048

  // Q fragments held in registers for the whole kernel
  bf16x8 aq[2];
  {
    const int qrow = qt * 64 + w * 16 + (l & 15);
#pragma unroll
    for (int ks = 0; ks < 2; ++ks)
      aq[ks] = *(const bf16x8*)&Q[head + (size_t)qrow * 64 + ks * 32 + (l >> 4) * 8];
  }

  f32x4 accO[4];
#pragma unroll
  for (int i = 0; i < 4; ++i) accO[i] = (f32x4){0.f, 0.f, 0.f, 0.f};
  float mrun[4], lrun[4];
#pragma unroll
  for (int i = 0; i < 4; ++i) { mrun[i] = -__builtin_inff(); lrun[i] = 0.f; }

  for (int st = 0; st <= qt; ++st) {
    __syncthreads();  // protect LDS from previous tile's readers
#pragma unroll
    for (int i = 0; i < 2; ++i) {
      const int q = (w * 2 + i) * 64 + l;
      const int r = q >> 3, sl = q & 7;
      const int ksw = (sl ^ (r & 7)) * 8;  // source-side XOR swizzle
      async16(&K[head + (size_t)(st * 64 + r) * 64 + ksw], &Ksh[(w * 2 + i) * 512]);
      async16(&Vt[head + (size_t)r * 2048 + st * 64 + ksw], &Vsh[(w * 2 + i) * 512]);
    }
    __syncthreads();

    // QK^T: S [16 q][64 s] per wave
    f32x4 s[4];
#pragma unroll
    for (int i = 0; i < 4; ++i) s[i] = (f32x4){0.f, 0.f, 0.f, 0.f};
#pragma unroll
    for (int ks = 0; ks < 2; ++ks)
#pragma unroll
      for (int nf = 0; nf < 4; ++nf) {
        const int row = nf * 16 + (l & 15);
        const int slot = (ks * 4 + (l >> 4)) ^ (row & 7);
        bf16x8 bk = *(const bf16x8*)&Ksh[row * 64 + slot * 8];
        s[nf] = __builtin_amdgcn_mfma_f32_16x16x32_bf16(aq[ks], bk, s[nf], 0, 0, 0);
      }

    const bool diag = (st == qt);
#pragma unroll
    for (int r = 0; r < 4; ++r) {
      const int qg = qt * 64 + w * 16 + (l >> 4) * 4 + r;
      float vals[4];
#pragma unroll
      for (int nf = 0; nf < 4; ++nf) {
        float v = s[nf][r] * 0.125f;
        if (diag) {
          const int sg = st * 64 + nf * 16 + (l & 15);
          if (sg > qg) v = -__builtin_inff();
        }
        vals[nf] = v;
      }
      float tmax = fmaxf(fmaxf(vals[0], vals[1]), fmaxf(vals[2], vals[3]));
#pragma unroll
      for (int off = 1; off < 16; off <<= 1) tmax = fmaxf(tmax, __shfl_xor(tmax, off));
      const float mnew = fmaxf(mrun[r], tmax);
      const float corr = __expf(mrun[r] - mnew);  // 0 on first tile
      float psum = 0.f;
      u16 pb[4];
#pragma unroll
      for (int nf = 0; nf < 4; ++nf) {
        const float p = __expf(vals[nf] - mnew);
        psum += p;
        pb[nf] = f2bf(p);
      }
#pragma unroll
      for (int off = 1; off < 16; off <<= 1) psum += __shfl_xor(psum, off);
      lrun[r] = lrun[r] * corr + psum;
      mrun[r] = mnew;
#pragma unroll
      for (int nd = 0; nd < 4; ++nd) accO[nd][r] *= corr;
      const int prow = (l >> 4) * 4 + r;
#pragma unroll
      for (int nf = 0; nf < 4; ++nf) Pl[w][prow * 72 + nf * 16 + (l & 15)] = pb[nf];
    }

    // PV: O += P[16 q][64 s] * Vt-tile[64 s][64 d]
#pragma unroll
    for (int ks2 = 0; ks2 < 2; ++ks2) {
      bf16x8 pf = *(const bf16x8*)&Pl[w][(l & 15) * 72 + (ks2 * 4 + (l >> 4)) * 8];
#pragma unroll
      for (int nd = 0; nd < 4; ++nd) {
        const int row = nd * 16 + (l & 15);
        const int slot = (ks2 * 4 + (l >> 4)) ^ (row & 7);
        bf16x8 vf = *(const bf16x8*)&Vsh[row * 64 + slot * 8];
        accO[nd] = __builtin_amdgcn_mfma_f32_16x16x32_bf16(pf, vf, accO[nd], 0, 0, 0);
      }
    }
  }

  const int b = bh >> 4, h = bh & 15;
#pragma unroll
  for (int nd = 0; nd < 4; ++nd)
#pragma unroll
    for (int r = 0; r < 4; ++r) {
      const int t = qt * 64 + w * 16 + (l >> 4) * 4 + r;
      const float o = accO[nd][r] / lrun[r];
      AO[(size_t)(b * 2048 + t) * 1024 + h * 64 + nd * 16 + (l & 15)] = f2bf(o);
    }
}

extern "C" void kernel_launch(void* const* d_in, const int* in_sizes, int n_in,
                              void* d_out, int out_size, void* d_ws, size_t ws_size,
                              hipStream_t stream) {
  const float* src = (const float*)d_in[0];
  const float* Wq = (const float*)d_in[2];
  const float* bq = (const float*)d_in[3];
  const float* Wk = (const float*)d_in[4];
  const float* bk = (const float*)d_in[5];
  const float* Wv = (const float*)d_in[6];
  const float* bv = (const float*)d_in[7];
  const float* Wo = (const float*)d_in[8];
  const float* bo = (const float*)d_in[9];
  float* out = (float*)d_out;

  char* ws = (char*)d_ws;
  u16* Wt = (u16*)(ws);                           // [4][1024][1024] bf16 (8 MB)
  u16* Xs = (u16*)(ws + 8ull * 1024 * 1024);      // [4096][1024] bf16 (8 MB)
  u16* Qb = (u16*)(ws + 16ull * 1024 * 1024);     // Q,K,Vt 3x4M elems (24 MB)
  u16* AO = (u16*)(ws + 40ull * 1024 * 1024);     // [4096][1024] bf16 (8 MB)

  kTransW<<<dim3(32, 32, 4), dim3(32, 8), 0, stream>>>(Wq, Wk, Wv, Wo, Wt);
  kPack<<<dim3(4096), dim3(256), 0, stream>>>(src, Xs);
  // fused QKV: N = 3072 -> 32 x 24 blocks
  kGemm<0><<<dim3(32 * 24), dim3(256), 0, stream>>>(Xs, Wt, bq, bk, bv, Qb, nullptr);
  kAttn<<<dim3(32, 32), dim3(256), 0, stream>>>(Qb, Qb + 4 * 1048576,
                                                Qb + 8 * 1048576, AO);
  // out proj: N = 1024 -> 32 x 8 blocks
  kGemm<1><<<dim3(32 * 8), dim3(256), 0, stream>>>(AO, Wt + 3ull * 1048576, bo,
                                                   nullptr, nullptr, nullptr, out);
}

// Round 2
// 145.520 us; speedup vs baseline: 1.2963x; 1.2963x over previous
//
#include <hip/hip_runtime.h>

typedef __bf16 bf16;
typedef bf16 bf16x8 __attribute__((ext_vector_type(8)));
typedef float f32x4 __attribute__((ext_vector_type(4)));
typedef unsigned short u16;
typedef u16 u16x4 __attribute__((ext_vector_type(4)));

typedef const __attribute__((address_space(1))) void* gptr_t;
typedef __attribute__((address_space(3))) void* sptr_t;

__device__ __forceinline__ void async16(const void* g, void* l) {
  __builtin_amdgcn_global_load_lds((gptr_t)g, (sptr_t)l, 16, 0, 0);
}
__device__ __forceinline__ u16 f2bf(float v) {
  return __builtin_bit_cast(u16, (bf16)v);
}

// ---------------- W transpose (f32 [K][N] -> bf16 [N][K]) ----------------
__global__ void kTransW(const float* __restrict__ Wq, const float* __restrict__ Wk,
                        const float* __restrict__ Wv, const float* __restrict__ Wo,
                        u16* __restrict__ Wt) {
  __shared__ float tile[32][33];
  const int z = blockIdx.z;
  const float* src = (z == 0) ? Wq : (z == 1) ? Wk : (z == 2) ? Wv : Wo;
  const int n0 = blockIdx.x * 32, k0 = blockIdx.y * 32;
  const int tx = threadIdx.x, ty = threadIdx.y;
#pragma unroll
  for (int j = 0; j < 4; ++j)
    tile[ty + j * 8][tx] = src[(size_t)(k0 + ty + j * 8) * 1024 + n0 + tx];
  __syncthreads();
#pragma unroll
  for (int j = 0; j < 4; ++j)
    Wt[(size_t)z * 1048576 + (size_t)(n0 + ty + j * 8) * 1024 + k0 + tx] =
        f2bf(tile[tx][ty + j * 8]);
}

// ---------------- src pack f32 -> bf16 ----------------
__global__ void kPack(const float* __restrict__ x, u16* __restrict__ y) {
  const int i = (blockIdx.x * 256 + threadIdx.x) * 4;
  float4 v = *(const float4*)&x[i];
  u16x4 o = {f2bf(v.x), f2bf(v.y), f2bf(v.z), f2bf(v.w)};
  *(u16x4*)&y[i] = o;
}

// ---------------- GEMM 128x128 tile, BK=32, 4 waves ----------------
// A [4096][1024] bf16 row-major; Bt [N][1024] bf16 (pre-transposed W).
// EPI=0: fused QKV scatter (Q scaled by 1/8; K at +4M elems, Vt at +8M elems)
// EPI=1: plain f32 out [4096][1024] + bias b0
template <int EPI>
__global__ __launch_bounds__(256, 2) void kGemm(
    const u16* __restrict__ A, const u16* __restrict__ Bt,
    const float* __restrict__ b0, const float* __restrict__ b1,
    const float* __restrict__ b2, u16* __restrict__ outQ,
    float* __restrict__ outF) {
  __shared__ __align__(16) u16 As[128 * 32];
  __shared__ __align__(16) u16 Bs[128 * 32];
  const int tid = threadIdx.x, l = tid & 63, w = tid >> 6;
  const int mb = blockIdx.x & 31, nb = blockIdx.x >> 5;
  const int mbase = mb * 128, nbase = nb * 128;
  const int wr = (w >> 1) * 64, wc = (w & 1) * 64;
  f32x4 acc[4][4];
#pragma unroll
  for (int i = 0; i < 4; ++i)
#pragma unroll
    for (int j = 0; j < 4; ++j) acc[i][j] = (f32x4){0.f, 0.f, 0.f, 0.f};

  for (int kt = 0; kt < 32; ++kt) {
    __syncthreads();
#pragma unroll
    for (int i = 0; i < 2; ++i) {
      const int q = (w * 2 + i) * 64 + l;
      const int r = q >> 2, sl = q & 3;
      const int ksw = (sl ^ ((r >> 1) & 3)) * 8;  // source-side XOR swizzle
      async16(&A[(size_t)(mbase + r) * 1024 + kt * 32 + ksw], &As[(w * 2 + i) * 512]);
      async16(&Bt[(size_t)(nbase + r) * 1024 + kt * 32 + ksw], &Bs[(w * 2 + i) * 512]);
    }
    __syncthreads();
    bf16x8 a[4], b[4];
#pragma unroll
    for (int mf = 0; mf < 4; ++mf) {
      const int row = wr + mf * 16 + (l & 15);
      const int slot = (l >> 4) ^ ((row >> 1) & 3);
      a[mf] = *(const bf16x8*)&As[row * 32 + slot * 8];
    }
#pragma unroll
    for (int nf = 0; nf < 4; ++nf) {
      const int row = wc + nf * 16 + (l & 15);
      const int slot = (l >> 4) ^ ((row >> 1) & 3);
      b[nf] = *(const bf16x8*)&Bs[row * 32 + slot * 8];
    }
#pragma unroll
    for (int mf = 0; mf < 4; ++mf)
#pragma unroll
      for (int nf = 0; nf < 4; ++nf)
        acc[mf][nf] = __builtin_amdgcn_mfma_f32_16x16x32_bf16(a[mf], b[nf],
                                                              acc[mf][nf], 0, 0, 0);
  }

  if constexpr (EPI == 0) {
    const int mat = nb >> 3;  // 0:Q 1:K 2:V (blocks never straddle 1024-col bnd)
    const float* bias = (mat == 0) ? b0 : (mat == 1) ? b1 : b2;
    const float qscale = (mat == 0) ? 0.125f : 1.0f;  // fold 1/sqrt(D) into Q
    u16* Qo = outQ;
    u16* Ko = outQ + 4 * 1048576;
    u16* Vo = outQ + 8 * 1048576;
#pragma unroll
    for (int nf = 0; nf < 4; ++nf) {
      const int n = nbase + wc + nf * 16 + (l & 15);
      const int c = n & 1023, h = c >> 6, d = c & 63;
      const float bsv = bias[c];
#pragma unroll
      for (int mf = 0; mf < 4; ++mf)
#pragma unroll
        for (int r = 0; r < 4; ++r) {
          const int m = mbase + wr + mf * 16 + (l >> 4) * 4 + r;
          const int bb = m >> 11, t = m & 2047;
          const u16 hv = f2bf((acc[mf][nf][r] + bsv) * qscale);
          if (mat == 0)
            Qo[((size_t)(bb * 16 + h) * 2048 + t) * 64 + d] = hv;
          else if (mat == 1)
            Ko[((size_t)(bb * 16 + h) * 2048 + t) * 64 + d] = hv;
          else  // V stored transposed: [b][h][d][t]
            Vo[((size_t)(bb * 16 + h) * 64 + d) * 2048 + t] = hv;
        }
    }
  } else {
#pragma unroll
    for (int nf = 0; nf < 4; ++nf) {
      const int n = nbase + wc + nf * 16 + (l & 15);
      const float bsv = b0[n];
#pragma unroll
      for (int mf = 0; mf < 4; ++mf)
#pragma unroll
        for (int r = 0; r < 4; ++r) {
          const int m = mbase + wr + mf * 16 + (l >> 4) * 4 + r;
          outF[(size_t)m * 1024 + n] = acc[mf][nf][r] + bsv;
        }
    }
  }
}

// ---------------- flash attention, causal, paired q-tiles ----------------
// Q,K: [b][h][2048][64] bf16 (Q pre-scaled by 1/8); Vt: [b][h][64][2048] bf16
// Block handles q-tiles qtA=pi and qtB=31-pi; KV tiles shared (causal prefix).
// K/V double-buffered in LDS; counted vmcnt keeps next tile's loads in flight.
__global__ __launch_bounds__(256, 2) void kAttn(const u16* __restrict__ Q,
                                                const u16* __restrict__ K,
                                                const u16* __restrict__ Vt,
                                                u16* __restrict__ AO) {
  __shared__ __align__(16) u16 Ksh[2][64 * 64];
  __shared__ __align__(16) u16 Vsh[2][64 * 64];
  __shared__ __align__(16) u16 Pl[4][16 * 72];  // per-wave P, row stride 72
  const int tid = threadIdx.x, l = tid & 63, w = tid >> 6;
  const int pi = blockIdx.x, bh = blockIdx.y;
  const int qtA = pi, qtB = 31 - pi;  // qtA <= 15 < 16 <= qtB
  const size_t head = (size_t)bh * 131072;  // 2048*64 == 64*2048

  // Q fragments for both tiles, held in registers for the whole kernel
  bf16x8 aqA[2], aqB[2];
  {
    const int qrA = qtA * 64 + w * 16 + (l & 15);
    const int qrB = qtB * 64 + w * 16 + (l & 15);
#pragma unroll
    for (int ks = 0; ks < 2; ++ks) {
      aqA[ks] = *(const bf16x8*)&Q[head + (size_t)qrA * 64 + ks * 32 + (l >> 4) * 8];
      aqB[ks] = *(const bf16x8*)&Q[head + (size_t)qrB * 64 + ks * 32 + (l >> 4) * 8];
    }
  }

  f32x4 accA[4], accB[4];
  float mA[4], lA[4], mB[4], lB[4];
#pragma unroll
  for (int i = 0; i < 4; ++i) {
    accA[i] = (f32x4){0.f, 0.f, 0.f, 0.f};
    accB[i] = (f32x4){0.f, 0.f, 0.f, 0.f};
    mA[i] = -__builtin_inff(); lA[i] = 0.f;
    mB[i] = -__builtin_inff(); lB[i] = 0.f;
  }

  auto stage = [&](int bufi, int st) {
#pragma unroll
    for (int i = 0; i < 2; ++i) {
      const int q = (w * 2 + i) * 64 + l;
      const int r = q >> 3, sl = q & 7;
      const int ksw = (sl ^ (r & 7)) * 8;  // source-side XOR swizzle
      async16(&K[head + (size_t)(st * 64 + r) * 64 + ksw], &Ksh[bufi][(w * 2 + i) * 512]);
      async16(&Vt[head + (size_t)r * 2048 + st * 64 + ksw], &Vsh[bufi][(w * 2 + i) * 512]);
    }
  };

  auto computeTile = [&](int st, int qt, bf16x8* aq, f32x4* accO, float* mrun,
                         float* lrun, int cur) {
    // QK^T: S [16 q][64 s] per wave
    f32x4 s[4];
#pragma unroll
    for (int i = 0; i < 4; ++i) s[i] = (f32x4){0.f, 0.f, 0.f, 0.f};
#pragma unroll
    for (int ks = 0; ks < 2; ++ks)
#pragma unroll
      for (int nf = 0; nf < 4; ++nf) {
        const int row = nf * 16 + (l & 15);
        const int slot = (ks * 4 + (l >> 4)) ^ (row & 7);
        bf16x8 bk = *(const bf16x8*)&Ksh[cur][row * 64 + slot * 8];
        s[nf] = __builtin_amdgcn_mfma_f32_16x16x32_bf16(aq[ks], bk, s[nf], 0, 0, 0);
      }

    const bool diag = (st == qt);
#pragma unroll
    for (int r = 0; r < 4; ++r) {
      const int qg = qt * 64 + w * 16 + (l >> 4) * 4 + r;
      float vals[4];
#pragma unroll
      for (int nf = 0; nf < 4; ++nf) {
        float v = s[nf][r];
        if (diag) {
          const int sg = st * 64 + nf * 16 + (l & 15);
          if (sg > qg) v = -__builtin_inff();
        }
        vals[nf] = v;
      }
      float tmax = fmaxf(fmaxf(vals[0], vals[1]), fmaxf(vals[2], vals[3]));
#pragma unroll
      for (int off = 1; off < 16; off <<= 1) tmax = fmaxf(tmax, __shfl_xor(tmax, off));
      const float mnew = fmaxf(mrun[r], tmax);
      const float corr = __expf(mrun[r] - mnew);  // 0 on first tile
      float psum = 0.f;
      u16 pb[4];
#pragma unroll
      for (int nf = 0; nf < 4; ++nf) {
        const float p = __expf(vals[nf] - mnew);
        psum += p;
        pb[nf] = f2bf(p);
      }
#pragma unroll
      for (int off = 1; off < 16; off <<= 1) psum += __shfl_xor(psum, off);
      lrun[r] = lrun[r] * corr + psum;
      mrun[r] = mnew;
#pragma unroll
      for (int nd = 0; nd < 4; ++nd) accO[nd][r] *= corr;
      const int prow = (l >> 4) * 4 + r;
#pragma unroll
      for (int nf = 0; nf < 4; ++nf) Pl[w][prow * 72 + nf * 16 + (l & 15)] = pb[nf];
    }

    // PV: O += P[16 q][64 s] * Vt-tile[64 s][64 d]
#pragma unroll
    for (int ks2 = 0; ks2 < 2; ++ks2) {
      bf16x8 pf = *(const bf16x8*)&Pl[w][(l & 15) * 72 + (ks2 * 4 + (l >> 4)) * 8];
#pragma unroll
      for (int nd = 0; nd < 4; ++nd) {
        const int row = nd * 16 + (l & 15);
        const int slot = (ks2 * 4 + (l >> 4)) ^ (row & 7);
        bf16x8 vf = *(const bf16x8*)&Vsh[cur][row * 64 + slot * 8];
        accO[nd] = __builtin_amdgcn_mfma_f32_16x16x32_bf16(pf, vf, accO[nd], 0, 0, 0);
      }
    }
  };

  stage(0, 0);
  for (int st = 0; st <= qtB; ++st) {
    const int cur = st & 1;
    if (st < qtB) {
      stage(cur ^ 1, st + 1);  // buffer last read at iter st-1; barrier passed
      asm volatile("s_waitcnt vmcnt(4)" ::: "memory");  // tile st landed
    } else {
      asm volatile("s_waitcnt vmcnt(0)" ::: "memory");
    }
    __builtin_amdgcn_s_barrier();
    __builtin_amdgcn_sched_barrier(0);

    computeTile(st, qtB, aqB, accB, mB, lB, cur);
    if (st <= qtA) computeTile(st, qtA, aqA, accA, mA, lA, cur);

    __builtin_amdgcn_s_barrier();  // all waves done reading buf[cur]
  }

  const int b = bh >> 4, h = bh & 15;
  auto writeOut = [&](int qt, f32x4* accO, float* lrun) {
#pragma unroll
    for (int nd = 0; nd < 4; ++nd)
#pragma unroll
      for (int r = 0; r < 4; ++r) {
        const int t = qt * 64 + w * 16 + (l >> 4) * 4 + r;
        const float o = accO[nd][r] / lrun[r];
        AO[(size_t)(b * 2048 + t) * 1024 + h * 64 + nd * 16 + (l & 15)] = f2bf(o);
      }
  };
  writeOut(qtA, accA, lA);
  writeOut(qtB, accB, lB);
}

extern "C" void kernel_launch(void* const* d_in, const int* in_sizes, int n_in,
                              void* d_out, int out_size, void* d_ws, size_t ws_size,
                              hipStream_t stream) {
  const float* src = (const float*)d_in[0];
  const float* Wq = (const float*)d_in[2];
  const float* bq = (const float*)d_in[3];
  const float* Wk = (const float*)d_in[4];
  const float* bk = (const float*)d_in[5];
  const float* Wv = (const float*)d_in[6];
  const float* bv = (const float*)d_in[7];
  const float* Wo = (const float*)d_in[8];
  const float* bo = (const float*)d_in[9];
  float* out = (float*)d_out;

  char* ws = (char*)d_ws;
  u16* Wt = (u16*)(ws);                           // [4][1024][1024] bf16 (8 MB)
  u16* Xs = (u16*)(ws + 8ull * 1024 * 1024);      // [4096][1024] bf16 (8 MB)
  u16* Qb = (u16*)(ws + 16ull * 1024 * 1024);     // Q,K,Vt 3x4M elems (24 MB)
  u16* AO = (u16*)(ws + 40ull * 1024 * 1024);     // [4096][1024] bf16 (8 MB)

  kTransW<<<dim3(32, 32, 4), dim3(32, 8), 0, stream>>>(Wq, Wk, Wv, Wo, Wt);
  kPack<<<dim3(4096), dim3(256), 0, stream>>>(src, Xs);
  // fused QKV: N = 3072 -> 32 x 24 blocks
  kGemm<0><<<dim3(32 * 24), dim3(256), 0, stream>>>(Xs, Wt, bq, bk, bv, Qb, nullptr);
  kAttn<<<dim3(16, 32), dim3(256), 0, stream>>>(Qb, Qb + 4 * 1048576,
                                                Qb + 8 * 1048576, AO);
  // out proj: N = 1024 -> 32 x 8 blocks
  kGemm<1><<<dim3(32 * 8), dim3(256), 0, stream>>>(AO, Wt + 3ull * 1048576, bo,
                                                   nullptr, nullptr, nullptr, out);
}

// Round 3
// 127.211 us; speedup vs baseline: 1.4829x; 1.1439x over previous
//
#include <hip/hip_runtime.h>

typedef __bf16 bf16;
typedef bf16 bf16x8 __attribute__((ext_vector_type(8)));
typedef float f32x4 __attribute__((ext_vector_type(4)));
typedef unsigned short u16;
typedef u16 u16x4 __attribute__((ext_vector_type(4)));

typedef const __attribute__((address_space(1))) void* gptr_t;
typedef __attribute__((address_space(3))) void* sptr_t;

__device__ __forceinline__ void async16(const void* g, void* l) {
  __builtin_amdgcn_global_load_lds((gptr_t)g, (sptr_t)l, 16, 0, 0);
}
__device__ __forceinline__ u16 f2bf(float v) {
  return __builtin_bit_cast(u16, (bf16)v);
}

// ---------------- W transpose (f32 [K][N] -> bf16 [N][K]) ----------------
__global__ void kTransW(const float* __restrict__ Wq, const float* __restrict__ Wk,
                        const float* __restrict__ Wv, const float* __restrict__ Wo,
                        u16* __restrict__ Wt) {
  __shared__ float tile[32][33];
  const int z = blockIdx.z;
  const float* src = (z == 0) ? Wq : (z == 1) ? Wk : (z == 2) ? Wv : Wo;
  const int n0 = blockIdx.x * 32, k0 = blockIdx.y * 32;
  const int tx = threadIdx.x, ty = threadIdx.y;
#pragma unroll
  for (int j = 0; j < 4; ++j)
    tile[ty + j * 8][tx] = src[(size_t)(k0 + ty + j * 8) * 1024 + n0 + tx];
  __syncthreads();
#pragma unroll
  for (int j = 0; j < 4; ++j)
    Wt[(size_t)z * 1048576 + (size_t)(n0 + ty + j * 8) * 1024 + k0 + tx] =
        f2bf(tile[tx][ty + j * 8]);
}

// ---------------- src pack f32 -> bf16 ----------------
__global__ void kPack(const float* __restrict__ x, u16* __restrict__ y) {
  const int i = (blockIdx.x * 256 + threadIdx.x) * 4;
  float4 v = *(const float4*)&x[i];
  u16x4 o = {f2bf(v.x), f2bf(v.y), f2bf(v.z), f2bf(v.w)};
  *(u16x4*)&y[i] = o;
}

// ---------------- GEMM 128x128 tile, BK=32, 4 waves ----------------
// A [4096][1024] bf16 row-major; Bt [N][1024] bf16 (pre-transposed W).
// EPI=0: fused QKV scatter (Q scaled by log2e/8; K at +4M, Vt at +8M elems)
// EPI=1: plain f32 out [4096][1024] + bias b0
template <int EPI>
__global__ __launch_bounds__(256, 2) void kGemm(
    const u16* __restrict__ A, const u16* __restrict__ Bt,
    const float* __restrict__ b0, const float* __restrict__ b1,
    const float* __restrict__ b2, u16* __restrict__ outQ,
    float* __restrict__ outF) {
  __shared__ __align__(16) u16 As[128 * 32];
  __shared__ __align__(16) u16 Bs[128 * 32];
  const int tid = threadIdx.x, l = tid & 63, w = tid >> 6;
  const int mb = blockIdx.x & 31, nb = blockIdx.x >> 5;
  const int mbase = mb * 128, nbase = nb * 128;
  const int wr = (w >> 1) * 64, wc = (w & 1) * 64;
  f32x4 acc[4][4];
#pragma unroll
  for (int i = 0; i < 4; ++i)
#pragma unroll
    for (int j = 0; j < 4; ++j) acc[i][j] = (f32x4){0.f, 0.f, 0.f, 0.f};

  for (int kt = 0; kt < 32; ++kt) {
    __syncthreads();
#pragma unroll
    for (int i = 0; i < 2; ++i) {
      const int q = (w * 2 + i) * 64 + l;
      const int r = q >> 2, sl = q & 3;
      const int ksw = (sl ^ ((r >> 1) & 3)) * 8;  // source-side XOR swizzle
      async16(&A[(size_t)(mbase + r) * 1024 + kt * 32 + ksw], &As[(w * 2 + i) * 512]);
      async16(&Bt[(size_t)(nbase + r) * 1024 + kt * 32 + ksw], &Bs[(w * 2 + i) * 512]);
    }
    __syncthreads();
    bf16x8 a[4], b[4];
#pragma unroll
    for (int mf = 0; mf < 4; ++mf) {
      const int row = wr + mf * 16 + (l & 15);
      const int slot = (l >> 4) ^ ((row >> 1) & 3);
      a[mf] = *(const bf16x8*)&As[row * 32 + slot * 8];
    }
#pragma unroll
    for (int nf = 0; nf < 4; ++nf) {
      const int row = wc + nf * 16 + (l & 15);
      const int slot = (l >> 4) ^ ((row >> 1) & 3);
      b[nf] = *(const bf16x8*)&Bs[row * 32 + slot * 8];
    }
#pragma unroll
    for (int mf = 0; mf < 4; ++mf)
#pragma unroll
      for (int nf = 0; nf < 4; ++nf)
        acc[mf][nf] = __builtin_amdgcn_mfma_f32_16x16x32_bf16(a[mf], b[nf],
                                                              acc[mf][nf], 0, 0, 0);
  }

  if constexpr (EPI == 0) {
    const int mat = nb >> 3;  // 0:Q 1:K 2:V (blocks never straddle 1024-col bnd)
    const float* bias = (mat == 0) ? b0 : (mat == 1) ? b1 : b2;
    // fold 1/sqrt(D) * log2(e) into Q so attention can use exp2 directly
    const float qscale = (mat == 0) ? 0.1803368801f : 1.0f;
    u16* Qo = outQ;
    u16* Ko = outQ + 4 * 1048576;
    u16* Vo = outQ + 8 * 1048576;
#pragma unroll
    for (int nf = 0; nf < 4; ++nf) {
      const int n = nbase + wc + nf * 16 + (l & 15);
      const int c = n & 1023, h = c >> 6, d = c & 63;
      const float bsv = bias[c];
#pragma unroll
      for (int mf = 0; mf < 4; ++mf)
#pragma unroll
        for (int r = 0; r < 4; ++r) {
          const int m = mbase + wr + mf * 16 + (l >> 4) * 4 + r;
          const int bb = m >> 11, t = m & 2047;
          const u16 hv = f2bf((acc[mf][nf][r] + bsv) * qscale);
          if (mat == 0)
            Qo[((size_t)(bb * 16 + h) * 2048 + t) * 64 + d] = hv;
          else if (mat == 1)
            Ko[((size_t)(bb * 16 + h) * 2048 + t) * 64 + d] = hv;
          else  // V stored transposed: [b][h][d][t]
            Vo[((size_t)(bb * 16 + h) * 64 + d) * 2048 + t] = hv;
        }
    }
  } else {
#pragma unroll
    for (int nf = 0; nf < 4; ++nf) {
      const int n = nbase + wc + nf * 16 + (l & 15);
      const float bsv = b0[n];
#pragma unroll
      for (int mf = 0; mf < 4; ++mf)
#pragma unroll
        for (int r = 0; r < 4; ++r) {
          const int m = mbase + wr + mf * 16 + (l >> 4) * 4 + r;
          outF[(size_t)m * 1024 + n] = acc[mf][nf][r] + bsv;
        }
    }
  }
}

// ---------------- flash attention, causal, paired q-tiles ----------------
// Q,K: [b][h][2048][64] bf16 (Q pre-scaled by log2e/8); Vt: [b][h][64][2048]
// Swapped QK^T (mfma(K,Q) -> S^T): each lane owns one q-column's 16 S-values;
// softmax reduce = in-register tree + 2 shfl_xor (vs 32 shfls row-oriented).
#define PSTR 88  // P row stride (u16): 176B rows -> ~2-way LDS conflicts (free)
__global__ __launch_bounds__(256, 2) void kAttn(const u16* __restrict__ Q,
                                                const u16* __restrict__ K,
                                                const u16* __restrict__ Vt,
                                                u16* __restrict__ AO) {
  __shared__ __align__(16) u16 Ksh[2][64 * 64];
  __shared__ __align__(16) u16 Vsh[2][64 * 64];
  __shared__ __align__(16) u16 Pl[4][16 * PSTR];
  const int tid = threadIdx.x, l = tid & 63, w = tid >> 6;
  const int g = l >> 4, c = l & 15;
  const int pi = blockIdx.x, bh = blockIdx.y;
  const int qtA = pi, qtB = 31 - pi;  // qtA <= 15 < 16 <= qtB
  const size_t head = (size_t)bh * 131072;  // 2048*64 == 64*2048

  // Q fragments for both tiles, held in registers for the whole kernel
  bf16x8 aqA[2], aqB[2];
  {
    const int qrA = qtA * 64 + w * 16 + c;
    const int qrB = qtB * 64 + w * 16 + c;
#pragma unroll
    for (int ks = 0; ks < 2; ++ks) {
      aqA[ks] = *(const bf16x8*)&Q[head + (size_t)qrA * 64 + ks * 32 + g * 8];
      aqB[ks] = *(const bf16x8*)&Q[head + (size_t)qrB * 64 + ks * 32 + g * 8];
    }
  }

  f32x4 accA[4], accB[4];
#pragma unroll
  for (int i = 0; i < 4; ++i) {
    accA[i] = (f32x4){0.f, 0.f, 0.f, 0.f};
    accB[i] = (f32x4){0.f, 0.f, 0.f, 0.f};
  }
  // column-oriented running max / denom (one scalar per lane; q = wave*16 + c)
  float mA = -__builtin_inff(), lA_ = 0.f;
  float mB = -__builtin_inff(), lB_ = 0.f;

  auto stage = [&](int bufi, int st) {
#pragma unroll
    for (int i = 0; i < 2; ++i) {
      const int q = (w * 2 + i) * 64 + l;
      const int r = q >> 3, sl = q & 7;
      const int ksw = (sl ^ (r & 7)) * 8;  // source-side XOR swizzle
      async16(&K[head + (size_t)(st * 64 + r) * 64 + ksw], &Ksh[bufi][(w * 2 + i) * 512]);
      async16(&Vt[head + (size_t)r * 2048 + st * 64 + ksw], &Vsh[bufi][(w * 2 + i) * 512]);
    }
  };

  auto computeTile = [&](int st, int qt, bf16x8* aq, f32x4* accO, float& mcol,
                         float& lcol, int cur) {
    // S^T = K * Q^T : per-lane: q-col = c, s(nf,r) = nf*16 + g*4 + r
    f32x4 sT[4];
#pragma unroll
    for (int i = 0; i < 4; ++i) sT[i] = (f32x4){0.f, 0.f, 0.f, 0.f};
#pragma unroll
    for (int ks = 0; ks < 2; ++ks)
#pragma unroll
      for (int nf = 0; nf < 4; ++nf) {
        const int row = nf * 16 + c;
        const int slot = (ks * 4 + g) ^ (row & 7);
        bf16x8 bk = *(const bf16x8*)&Ksh[cur][row * 64 + slot * 8];
        sT[nf] = __builtin_amdgcn_mfma_f32_16x16x32_bf16(bk, aq[ks], sT[nf], 0, 0, 0);
      }

    float v[16];
#pragma unroll
    for (int nf = 0; nf < 4; ++nf)
#pragma unroll
      for (int r = 0; r < 4; ++r) v[nf * 4 + r] = sT[nf][r];
    if (st == qt) {  // wave-uniform branch: mask only on the diagonal tile
      const int qg = w * 16 + c;
#pragma unroll
      for (int nf = 0; nf < 4; ++nf)
#pragma unroll
        for (int r = 0; r < 4; ++r)
          if (nf * 16 + g * 4 + r > qg) v[nf * 4 + r] = -__builtin_inff();
    }

    // column max: in-register tree + 2 cross-lane steps
    float t0 = fmaxf(v[0], v[1]), t1 = fmaxf(v[2], v[3]);
    float t2 = fmaxf(v[4], v[5]), t3 = fmaxf(v[6], v[7]);
    float t4 = fmaxf(v[8], v[9]), t5 = fmaxf(v[10], v[11]);
    float t6 = fmaxf(v[12], v[13]), t7 = fmaxf(v[14], v[15]);
    float tm = fmaxf(fmaxf(fmaxf(t0, t1), fmaxf(t2, t3)),
                     fmaxf(fmaxf(t4, t5), fmaxf(t6, t7)));
    tm = fmaxf(tm, __shfl_xor(tm, 16));
    tm = fmaxf(tm, __shfl_xor(tm, 32));
    const float mnew = fmaxf(mcol, tm);
    const float corr = __builtin_exp2f(mcol - mnew);  // 0 on first tile

    float p[16];
#pragma unroll
    for (int i = 0; i < 16; ++i) p[i] = __builtin_exp2f(v[i] - mnew);
    // P -> LDS as bf16, 4x ds_write_b64 (s-consecutive quads)
#pragma unroll
    for (int nf = 0; nf < 4; ++nf) {
      u16x4 q4 = {f2bf(p[nf * 4 + 0]), f2bf(p[nf * 4 + 1]),
                  f2bf(p[nf * 4 + 2]), f2bf(p[nf * 4 + 3])};
      *(u16x4*)&Pl[w][c * PSTR + nf * 16 + g * 4] = q4;
    }
    // column sum tree + 2 cross-lane steps
    float s0 = (p[0] + p[1]) + (p[2] + p[3]);
    float s1 = (p[4] + p[5]) + (p[6] + p[7]);
    float s2 = (p[8] + p[9]) + (p[10] + p[11]);
    float s3 = (p[12] + p[13]) + (p[14] + p[15]);
    float ps = (s0 + s1) + (s2 + s3);
    ps += __shfl_xor(ps, 16);
    ps += __shfl_xor(ps, 32);
    lcol = lcol * corr + ps;
    mcol = mnew;

    // rescale O (row-oriented): broadcast corr from column owners
#pragma unroll
    for (int r = 0; r < 4; ++r) {
      const float cr = __shfl(corr, g * 4 + r);
#pragma unroll
      for (int nd = 0; nd < 4; ++nd) accO[nd][r] *= cr;
    }

    // PV: O += P[16 q][64 s] * Vt-tile[64 s][64 d]
#pragma unroll
    for (int ks2 = 0; ks2 < 2; ++ks2) {
      bf16x8 pf = *(const bf16x8*)&Pl[w][c * PSTR + ks2 * 32 + g * 8];
#pragma unroll
      for (int nd = 0; nd < 4; ++nd) {
        const int row = nd * 16 + c;
        const int slot = (ks2 * 4 + g) ^ (row & 7);
        bf16x8 vf = *(const bf16x8*)&Vsh[cur][row * 64 + slot * 8];
        accO[nd] = __builtin_amdgcn_mfma_f32_16x16x32_bf16(pf, vf, accO[nd], 0, 0, 0);
      }
    }
  };

  stage(0, 0);
  for (int st = 0; st <= qtB; ++st) {
    const int cur = st & 1;
    if (st < qtB) {
      stage(cur ^ 1, st + 1);  // buffer last read at iter st-1; barrier passed
      asm volatile("s_waitcnt vmcnt(4)" ::: "memory");  // tile st landed
    } else {
      asm volatile("s_waitcnt vmcnt(0)" ::: "memory");
    }
    __builtin_amdgcn_s_barrier();
    __builtin_amdgcn_sched_barrier(0);

    computeTile(st, qtB, aqB, accB, mB, lB_, cur);
    if (st <= qtA) computeTile(st, qtA, aqA, accA, mA, lA_, cur);

    __builtin_amdgcn_s_barrier();  // all waves done reading buf[cur]
  }

  const int b = bh >> 4, h = bh & 15;
  auto writeOut = [&](int qt, f32x4* accO, float lcol) {
#pragma unroll
    for (int r = 0; r < 4; ++r) {
      const float lr = __shfl(lcol, g * 4 + r);
      const float rin = 1.0f / lr;
      const int t = qt * 64 + w * 16 + g * 4 + r;
#pragma unroll
      for (int nd = 0; nd < 4; ++nd)
        AO[(size_t)(b * 2048 + t) * 1024 + h * 64 + nd * 16 + c] =
            f2bf(accO[nd][r] * rin);
    }
  };
  writeOut(qtA, accA, lA_);
  writeOut(qtB, accB, lB_);
}

extern "C" void kernel_launch(void* const* d_in, const int* in_sizes, int n_in,
                              void* d_out, int out_size, void* d_ws, size_t ws_size,
                              hipStream_t stream) {
  const float* src = (const float*)d_in[0];
  const float* Wq = (const float*)d_in[2];
  const float* bq = (const float*)d_in[3];
  const float* Wk = (const float*)d_in[4];
  const float* bk = (const float*)d_in[5];
  const float* Wv = (const float*)d_in[6];
  const float* bv = (const float*)d_in[7];
  const float* Wo = (const float*)d_in[8];
  const float* bo = (const float*)d_in[9];
  float* out = (float*)d_out;

  char* ws = (char*)d_ws;
  u16* Wt = (u16*)(ws);                           // [4][1024][1024] bf16 (8 MB)
  u16* Xs = (u16*)(ws + 8ull * 1024 * 1024);      // [4096][1024] bf16 (8 MB)
  u16* Qb = (u16*)(ws + 16ull * 1024 * 1024);     // Q,K,Vt 3x4M elems (24 MB)
  u16* AO = (u16*)(ws + 40ull * 1024 * 1024);     // [4096][1024] bf16 (8 MB)

  kTransW<<<dim3(32, 32, 4), dim3(32, 8), 0, stream>>>(Wq, Wk, Wv, Wo, Wt);
  kPack<<<dim3(4096), dim3(256), 0, stream>>>(src, Xs);
  // fused QKV: N = 3072 -> 32 x 24 blocks
  kGemm<0><<<dim3(32 * 24), dim3(256), 0, stream>>>(Xs, Wt, bq, bk, bv, Qb, nullptr);
  kAttn<<<dim3(16, 32), dim3(256), 0, stream>>>(Qb, Qb + 4 * 1048576,
                                                Qb + 8 * 1048576, AO);
  // out proj: N = 1024 -> 32 x 8 blocks
  kGemm<1><<<dim3(32 * 8), dim3(256), 0, stream>>>(AO, Wt + 3ull * 1048576, bo,
                                                   nullptr, nullptr, nullptr, out);
}